// Round 1
// baseline (4612.936 us; speedup 1.0000x reference)
//
#include <hip/hip_runtime.h>

#define E_N 200000
#define T_N 2000000
#define H_N 256
#define INT_N 64

__device__ __forceinline__ float silu_f(float v){
    return v / (1.0f + __expf(-v));
}

// ---------------- Generic GEMM: C = epi(A[M,K] @ W[K,N] + bias) ----------------
// BM=128, BN=64, BK=16; 256 threads; thread tile 8x4.
// epi: optional silu, then optional elementwise mul (M x N), then optional add (M x N).
__global__ __launch_bounds__(256) void gemm_f32(
    const float* __restrict__ A, const float* __restrict__ W,
    const float* __restrict__ bias, const float* __restrict__ mulmat,
    const float* __restrict__ addmat, float* __restrict__ C,
    int M, int N, int K, int do_silu)
{
    __shared__ float As[16][132];   // [k][m], padded to dodge bank conflicts
    __shared__ float Ws[16][64];    // [k][n]
    const int tid = threadIdx.x;
    const int tx = tid & 15;
    const int ty = tid >> 4;
    const int m0 = blockIdx.x * 128;
    const int n0 = blockIdx.y * 64;

    float acc[8][4];
    #pragma unroll
    for (int r=0;r<8;r++)
        #pragma unroll
        for (int c=0;c<4;c++) acc[r][c]=0.f;

    const int arow = tid >> 2;        // 0..63
    const int ak4  = (tid & 3) * 4;   // 0,4,8,12
    const int wrow = tid >> 4;        // 0..15
    const int wcol = (tid & 15) * 4;  // 0..60

    for (int k0 = 0; k0 < K; k0 += 16){
        #pragma unroll
        for (int i=0;i<2;i++){
            const int row = arow + i*64;
            int grow = m0 + row; if (grow >= M) grow = M-1;  // clamp; store is guarded
            const float4 av = *(const float4*)&A[(long)grow*K + k0 + ak4];
            As[ak4+0][row] = av.x;
            As[ak4+1][row] = av.y;
            As[ak4+2][row] = av.z;
            As[ak4+3][row] = av.w;
        }
        {
            const float4 wv = *(const float4*)&W[(long)(k0+wrow)*N + n0 + wcol];
            *(float4*)&Ws[wrow][wcol] = wv;
        }
        __syncthreads();
        #pragma unroll
        for (int kk=0;kk<16;kk++){
            float a[8], b[4];
            const float4 a0 = *(const float4*)&As[kk][ty*8];
            const float4 a1 = *(const float4*)&As[kk][ty*8+4];
            a[0]=a0.x; a[1]=a0.y; a[2]=a0.z; a[3]=a0.w;
            a[4]=a1.x; a[5]=a1.y; a[6]=a1.z; a[7]=a1.w;
            const float4 b0 = *(const float4*)&Ws[kk][tx*4];
            b[0]=b0.x; b[1]=b0.y; b[2]=b0.z; b[3]=b0.w;
            #pragma unroll
            for (int r=0;r<8;r++)
                #pragma unroll
                for (int c=0;c<4;c++)
                    acc[r][c] = __builtin_fmaf(a[r], b[c], acc[r][c]);
        }
        __syncthreads();
    }

    const int colb = n0 + tx*4;
    float4 bv = make_float4(0.f,0.f,0.f,0.f);
    if (bias) bv = *(const float4*)&bias[colb];
    #pragma unroll
    for (int r=0;r<8;r++){
        const int row = m0 + ty*8 + r;
        if (row >= M) continue;
        float4 v = make_float4(acc[r][0]+bv.x, acc[r][1]+bv.y,
                               acc[r][2]+bv.z, acc[r][3]+bv.w);
        if (do_silu){ v.x=silu_f(v.x); v.y=silu_f(v.y); v.z=silu_f(v.z); v.w=silu_f(v.w); }
        const long off = (long)row*N + colb;
        if (mulmat){ const float4 m4 = *(const float4*)&mulmat[off];
                     v.x*=m4.x; v.y*=m4.y; v.z*=m4.z; v.w*=m4.w; }
        if (addmat){ const float4 a4 = *(const float4*)&addmat[off];
                     v.x+=a4.x; v.y+=a4.y; v.z+=a4.z; v.w+=a4.w; }
        *(float4*)&C[off] = v;
    }
}

// ------------- tiny weight-product precompute: W12 = W_rbf1@W_rbf2 (6x256),
//               Wsbf = W_sbf1@W_sbf2 (42x64) -------------
__global__ void precompute_w(const float* __restrict__ Wr1, const float* __restrict__ Wr2,
                             const float* __restrict__ Ws1, const float* __restrict__ Ws2,
                             float* __restrict__ W12, float* __restrict__ Wsbf)
{
    const int tid = blockIdx.x*256 + threadIdx.x;
    if (tid < 6*256){
        const int i = tid >> 8, n = tid & 255;
        float s = 0.f;
        #pragma unroll
        for (int j=0;j<8;j++) s += Wr1[i*8+j]*Wr2[j*256+n];
        W12[tid] = s;
    }
    if (tid < 42*64){
        const int i = tid >> 6, n = tid & 63;
        float s = 0.f;
        #pragma unroll
        for (int j=0;j<8;j++) s += Ws1[i*8+j]*Ws2[j*64+n];
        Wsbf[tid] = s;
    }
}

// ------------- rbf_e[E,256] = rbf[E,6] @ W12[6,256] -------------
__global__ __launch_bounds__(256) void rbf_expand(
    const float* __restrict__ rbf, const float* __restrict__ W12,
    float* __restrict__ out)
{
    const long idx = (long)blockIdx.x*256 + threadIdx.x;
    const int e = (int)(idx >> 8);
    const int n = (int)(idx & 255);
    if (e >= E_N) return;
    float s = 0.f;
    #pragma unroll
    for (int i=0;i<6;i++) s += rbf[e*6+i] * W12[i*256+n];
    out[idx] = s;
}

__global__ __launch_bounds__(256) void zero_f32(float* __restrict__ p, long n){
    const long i = ((long)blockIdx.x*256 + threadIdx.x)*4;
    if (i < n) *(float4*)&p[i] = make_float4(0.f,0.f,0.f,0.f);
}

// ------------- triplet stage: agg[ji] += down[kj] * (sbf_row @ Wsbf) -------------
// One wave per triplet (lane = INT channel); 64 triplets' sbf rows staged in LDS per block tile.
__global__ __launch_bounds__(256) void triplet_kernel(
    const float* __restrict__ down, const float* __restrict__ sbf,
    const int* __restrict__ idx_kj, const int* __restrict__ idx_ji,
    const float* __restrict__ Wsbf, float* __restrict__ agg)
{
    __shared__ float lds_sbf[64*44];   // 44-float rows (16B aligned)
    const int lane = threadIdx.x & 63;
    const int wave = threadIdx.x >> 6;
    float w[42];
    #pragma unroll
    for (int k=0;k<42;k++) w[k] = Wsbf[k*64 + lane];

    const int ntiles = T_N/64;   // 31250 exactly
    for (int tile = blockIdx.x; tile < ntiles; tile += gridDim.x){
        const long t0 = (long)tile*64;
        __syncthreads();   // protect previous tile's reads
        for (int i = threadIdx.x; i < 64*42; i += 256){
            const int tr = i/42, kk = i - tr*42;
            lds_sbf[tr*44 + kk] = sbf[t0*42 + i];
        }
        __syncthreads();
        #pragma unroll 4
        for (int j=0;j<16;j++){
            const int tl = wave*16 + j;
            const long t = t0 + tl;
            const int kj = idx_kj[t];
            const int ji = idx_ji[t];
            const float g = down[(long)kj*64 + lane];
            const float* srow = &lds_sbf[tl*44];
            float s = 0.f;
            #pragma unroll
            for (int k=0;k<42;k++) s += srow[k]*w[k];
            atomicAdd(&agg[(long)ji*64 + lane], g*s);
        }
    }
}

extern "C" void kernel_launch(void* const* d_in, const int* in_sizes, int n_in,
                              void* d_out, int out_size, void* d_ws, size_t ws_size,
                              hipStream_t stream)
{
    const float* x      = (const float*)d_in[0];
    const float* rbf    = (const float*)d_in[1];
    const float* sbf    = (const float*)d_in[2];
    const int*   idx_kj = (const int*)d_in[3];
    const int*   idx_ji = (const int*)d_in[4];
    const float* W_rbf1 = (const float*)d_in[5];
    const float* W_rbf2 = (const float*)d_in[6];
    const float* W_sbf1 = (const float*)d_in[7];
    const float* W_sbf2 = (const float*)d_in[8];
    const float* W_kj   = (const float*)d_in[9];
    const float* b_kj   = (const float*)d_in[10];
    const float* W_ji   = (const float*)d_in[11];
    const float* b_ji   = (const float*)d_in[12];
    const float* W_down = (const float*)d_in[13];
    const float* W_up   = (const float*)d_in[14];
    const float* rb_W1  = (const float*)d_in[15];
    const float* rb_b1  = (const float*)d_in[16];
    const float* rb_W2  = (const float*)d_in[17];
    const float* rb_b2  = (const float*)d_in[18];
    const float* W_lin  = (const float*)d_in[19];
    const float* b_lin  = (const float*)d_in[20];
    const float* ra_W1  = (const float*)d_in[21];
    const float* ra_b1  = (const float*)d_in[22];
    const float* ra_W2  = (const float*)d_in[23];
    const float* ra_b2  = (const float*)d_in[24];
    float* out = (float*)d_out;

    float* ws   = (float*)d_ws;
    float* W12  = ws;              // 1536 floats
    float* Wsbf = ws + 2048;       // 2688 floats
    float* bufA = ws + 8192;                      // E*H
    float* bufB = bufA + (long)E_N*H_N;           // E*H
    float* bufC = bufB + (long)E_N*H_N;           // E*H
    float* bufD = bufC + (long)E_N*H_N;           // E*64
    float* bufE = bufD + (long)E_N*INT_N;         // E*64

    const dim3 blk(256);
    const dim3 g256((E_N+127)/128, H_N/64);
    const dim3 g64((E_N+127)/128, 1);

    // factored small weight products
    precompute_w<<<11, blk, 0, stream>>>(W_rbf1, W_rbf2, W_sbf1, W_sbf2, W12, Wsbf);
    // rbf_e -> bufA
    rbf_expand<<<E_N, blk, 0, stream>>>(rbf, W12, bufA);
    // x_ji = silu(x@W_ji + b_ji) -> bufB
    gemm_f32<<<g256, blk, 0, stream>>>(x, W_ji, b_ji, nullptr, nullptr, bufB, E_N, H_N, H_N, 1);
    // x_kj = silu(x@W_kj + b_kj) * rbf_e -> bufC
    gemm_f32<<<g256, blk, 0, stream>>>(x, W_kj, b_kj, bufA, nullptr, bufC, E_N, H_N, H_N, 1);
    // down = silu(x_kj @ W_down) -> bufD   [E,64]
    gemm_f32<<<g64, blk, 0, stream>>>(bufC, W_down, nullptr, nullptr, nullptr, bufD, E_N, INT_N, H_N, 1);
    // agg = 0
    zero_f32<<<(E_N*INT_N/4+255)/256, blk, 0, stream>>>(bufE, (long)E_N*INT_N);
    // scatter: agg[ji] += down[kj] * (sbf@Wsbf)
    triplet_kernel<<<16384, blk, 0, stream>>>(bufD, sbf, idx_kj, idx_ji, Wsbf, bufE);
    // h = silu(agg@W_up) + x_ji -> bufA
    gemm_f32<<<g256, blk, 0, stream>>>(bufE, W_up, nullptr, nullptr, bufB, bufA, E_N, H_N, INT_N, 1);
    // before-skip: t1 = silu(h@rbW1+b1) -> bufC
    gemm_f32<<<g256, blk, 0, stream>>>(bufA, rb_W1, rb_b1, nullptr, nullptr, bufC, E_N, H_N, H_N, 1);
    // h = h + silu(t1@rbW2+b2) -> bufB
    gemm_f32<<<g256, blk, 0, stream>>>(bufC, rb_W2, rb_b2, nullptr, bufA, bufB, E_N, H_N, H_N, 1);
    // h = silu(h@W_lin+b_lin) + x -> bufA
    gemm_f32<<<g256, blk, 0, stream>>>(bufB, W_lin, b_lin, nullptr, x, bufA, E_N, H_N, H_N, 1);
    // after-skip 0
    gemm_f32<<<g256, blk, 0, stream>>>(bufA, ra_W1, ra_b1, nullptr, nullptr, bufC, E_N, H_N, H_N, 1);
    gemm_f32<<<g256, blk, 0, stream>>>(bufC, ra_W2, ra_b2, nullptr, bufA, bufB, E_N, H_N, H_N, 1);
    // after-skip 1 (final write straight to d_out)
    gemm_f32<<<g256, blk, 0, stream>>>(bufB, ra_W1+65536, ra_b1+256, nullptr, nullptr, bufC, E_N, H_N, H_N, 1);
    gemm_f32<<<g256, blk, 0, stream>>>(bufC, ra_W2+65536, ra_b2+256, nullptr, bufB, out, E_N, H_N, H_N, 1);
}

// Round 2
// 2964.776 us; speedup vs baseline: 1.5559x; 1.5559x over previous
//
#include <hip/hip_runtime.h>

#define E_N 200000
#define T_N 2000000
#define H_N 256
#define INT_N 64

typedef unsigned short ushortT;
typedef __attribute__((ext_vector_type(8))) short short8;    // 8 x bf16 (4 VGPRs)
typedef __attribute__((ext_vector_type(4))) float f32x4;     // MFMA accumulator
typedef __attribute__((ext_vector_type(8))) unsigned short ushort8;

__device__ __forceinline__ float silu_f(float v){
    return v / (1.0f + __expf(-v));
}
__device__ __forceinline__ ushortT f2b(float f){
    unsigned int u = __float_as_uint(f);
    unsigned int r = (u + 0x7fffu + ((u >> 16) & 1u)) >> 16;   // RNE
    return (ushortT)r;
}
__device__ __forceinline__ float b2f(ushortT h){
    return __uint_as_float(((unsigned int)h) << 16);
}

#define GLOAD_LDS16(gp, lp) \
    __builtin_amdgcn_global_load_lds((const __attribute__((address_space(1))) void*)(gp), \
                                     (__attribute__((address_space(3))) void*)(lp), 16, 0, 0)

// ---------------- bf16 MFMA GEMM: C = epi(A[M,K] @ Wt[N,K]^T + bias) ----------------
// BM=128, BN in {128,64}, BK=32; 256 threads (4 waves).
// BN=128: 2x2 waves, each 64x64 (MR=4). BN=64: 4x1 waves, each 32x64 (MR=2).
template<int BN, int MR>
__global__ __launch_bounds__(256) void gemm_mfma(
    const ushortT* __restrict__ A, const ushortT* __restrict__ Wt,
    const float* __restrict__ bias, const ushortT* __restrict__ mulmat,
    const ushortT* __restrict__ addmat, void* __restrict__ Cout,
    int M, int N, int K, int do_silu, int out_f32)
{
    __shared__ ushortT As[128*32];
    __shared__ ushortT Bs[BN*32];
    const int tid  = threadIdx.x;
    const int lane = tid & 63;
    const int wave = tid >> 6;
    const int m0 = blockIdx.x * 128;
    const int n0 = blockIdx.y * BN;

    const int wrow = (BN == 128) ? (wave & 1) * 64 : wave * 32;
    const int wcol = (BN == 128) ? (wave >> 1) * 64 : 0;

    f32x4 acc[MR][4];
    #pragma unroll
    for (int r=0;r<MR;r++)
        #pragma unroll
        for (int c=0;c<4;c++) acc[r][c] = (f32x4){0.f,0.f,0.f,0.f};

    const int arow = tid >> 2;        // 0..63
    const int ak   = (tid & 3) * 8;   // element offset along K
    const int l15  = lane & 15;
    const int q8   = (lane >> 4) * 8;

    for (int k0 = 0; k0 < K; k0 += 32){
        // stage A tile (128 x 32 bf16, contiguous rows of 64B)
        #pragma unroll
        for (int i=0;i<2;i++){
            int gr = m0 + i*64 + arow; if (gr >= M) gr = M - 1;
            const ushortT* gp = A + (size_t)gr * K + k0 + ak;
            GLOAD_LDS16(gp, &As[i*2048 + wave*512]);
        }
        // stage B tile (BN x 32 bf16)
        #pragma unroll
        for (int i=0;i<BN/64;i++){
            const ushortT* gp = Wt + (size_t)(n0 + i*64 + arow) * K + k0 + ak;
            GLOAD_LDS16(gp, &Bs[i*2048 + wave*512]);
        }
        __syncthreads();   // drains vmcnt(0) + visibility

        short8 af[MR], bf[4];
        #pragma unroll
        for (int r=0;r<MR;r++) af[r] = *(const short8*)&As[(wrow + r*16 + l15)*32 + q8];
        #pragma unroll
        for (int c=0;c<4;c++)  bf[c] = *(const short8*)&Bs[(wcol + c*16 + l15)*32 + q8];
        #pragma unroll
        for (int r=0;r<MR;r++)
            #pragma unroll
            for (int c=0;c<4;c++)
                acc[r][c] = __builtin_amdgcn_mfma_f32_16x16x32_bf16(af[r], bf[c], acc[r][c], 0, 0, 0);
        __syncthreads();   // before next tile overwrites LDS
    }

    // epilogue: C/D layout col=lane&15, row=(lane>>4)*4+reg
    const int q = lane >> 4;
    #pragma unroll
    for (int r=0;r<MR;r++){
        #pragma unroll
        for (int e=0;e<4;e++){
            const int row = m0 + wrow + r*16 + q*4 + e;
            if (row >= M) continue;
            #pragma unroll
            for (int c=0;c<4;c++){
                const int col = n0 + wcol + c*16 + l15;
                float v = acc[r][c][e];
                if (bias) v += bias[col];
                if (do_silu) v = silu_f(v);
                const size_t off = (size_t)row * N + col;
                if (mulmat) v *= b2f(mulmat[off]);
                if (addmat) v += b2f(addmat[off]);
                if (out_f32) ((float*)Cout)[off] = v;
                else         ((ushortT*)Cout)[off] = f2b(v);
            }
        }
    }
}

// ------------- tiny weight-product precompute (f32) -------------
__global__ void precompute_w(const float* __restrict__ Wr1, const float* __restrict__ Wr2,
                             const float* __restrict__ Ws1, const float* __restrict__ Ws2,
                             float* __restrict__ W12, float* __restrict__ Wsbf)
{
    const int tid = blockIdx.x*256 + threadIdx.x;
    if (tid < 6*256){
        const int i = tid >> 8, n = tid & 255;
        float s = 0.f;
        #pragma unroll
        for (int j=0;j<8;j++) s += Wr1[i*8+j]*Wr2[j*256+n];
        W12[tid] = s;
    }
    if (tid < 42*64){
        const int i = tid >> 6, n = tid & 63;
        float s = 0.f;
        #pragma unroll
        for (int j=0;j<8;j++) s += Ws1[i*8+j]*Ws2[j*64+n];
        Wsbf[tid] = s;
    }
}

// ------------- all weight transposes (f32 [K,N] -> bf16 [N,K]) in one launch -------------
struct WTList { const float* src[11]; int K[11]; int N[11]; };
__global__ void transpose_weights(WTList L, ushortT* __restrict__ dst){
    const int w = blockIdx.y;
    const float* S = L.src[w];
    const int K = L.K[w], N = L.N[w];
    ushortT* D = dst + (size_t)w * 65536;
    for (int i = blockIdx.x*256 + threadIdx.x; i < K*N; i += gridDim.x*256){
        const int k = i / N, n = i - k*N;
        D[n*K + k] = f2b(S[i]);
    }
}

// ------------- f32 -> bf16 bulk convert (8 elems/thread) -------------
__global__ __launch_bounds__(256) void f32_to_bf16_k(
    const float* __restrict__ s, ushortT* __restrict__ d, long n)
{
    const long i = ((long)blockIdx.x*256 + threadIdx.x)*8;
    if (i >= n) return;
    const float4 a = *(const float4*)&s[i];
    const float4 b = *(const float4*)&s[i+4];
    ushort8 o;
    o[0]=f2b(a.x); o[1]=f2b(a.y); o[2]=f2b(a.z); o[3]=f2b(a.w);
    o[4]=f2b(b.x); o[5]=f2b(b.y); o[6]=f2b(b.z); o[7]=f2b(b.w);
    *(ushort8*)&d[i] = o;
}

// ------------- rbf_e[E,256] = rbf[E,6] @ W12[6,256], bf16 out -------------
__global__ __launch_bounds__(256) void rbf_expand(
    const float* __restrict__ rbf, const float* __restrict__ W12,
    ushortT* __restrict__ out)
{
    const long idx = (long)blockIdx.x*256 + threadIdx.x;
    const int e = (int)(idx >> 8);
    const int n = (int)(idx & 255);
    if (e >= E_N) return;
    float s = 0.f;
    #pragma unroll
    for (int i=0;i<6;i++) s += rbf[e*6+i] * W12[i*256+n];
    out[idx] = f2b(s);
}

__global__ __launch_bounds__(256) void zero_f32(float* __restrict__ p, long n){
    const long i = ((long)blockIdx.x*256 + threadIdx.x)*4;
    if (i < n) *(float4*)&p[i] = make_float4(0.f,0.f,0.f,0.f);
}

// ------------- triplet stage: agg[ji] += down[kj] * (sbf_row @ Wsbf) -------------
__global__ __launch_bounds__(256) void triplet_kernel(
    const float* __restrict__ down, const float* __restrict__ sbf,
    const int* __restrict__ idx_kj, const int* __restrict__ idx_ji,
    const float* __restrict__ Wsbf, float* __restrict__ agg)
{
    __shared__ float lds_sbf[64*44];
    const int lane = threadIdx.x & 63;
    const int wave = threadIdx.x >> 6;
    float w[42];
    #pragma unroll
    for (int k=0;k<42;k++) w[k] = Wsbf[k*64 + lane];

    const int ntiles = T_N/64;
    for (int tile = blockIdx.x; tile < ntiles; tile += gridDim.x){
        const long t0 = (long)tile*64;
        __syncthreads();
        for (int i = threadIdx.x; i < 64*42; i += 256){
            const int tr = i/42, kk = i - tr*42;
            lds_sbf[tr*44 + kk] = sbf[t0*42 + i];
        }
        __syncthreads();
        #pragma unroll 4
        for (int j=0;j<16;j++){
            const int tl = wave*16 + j;
            const long t = t0 + tl;
            const int kj = idx_kj[t];
            const int ji = idx_ji[t];
            const float g = down[(long)kj*64 + lane];
            const float* srow = &lds_sbf[tl*44];
            float s = 0.f;
            #pragma unroll
            for (int k=0;k<42;k++) s += srow[k]*w[k];
            atomicAdd(&agg[(long)ji*64 + lane], g*s);
        }
    }
}

extern "C" void kernel_launch(void* const* d_in, const int* in_sizes, int n_in,
                              void* d_out, int out_size, void* d_ws, size_t ws_size,
                              hipStream_t stream)
{
    const float* x      = (const float*)d_in[0];
    const float* rbf    = (const float*)d_in[1];
    const float* sbf    = (const float*)d_in[2];
    const int*   idx_kj = (const int*)d_in[3];
    const int*   idx_ji = (const int*)d_in[4];
    const float* W_rbf1 = (const float*)d_in[5];
    const float* W_rbf2 = (const float*)d_in[6];
    const float* W_sbf1 = (const float*)d_in[7];
    const float* W_sbf2 = (const float*)d_in[8];
    const float* W_kj   = (const float*)d_in[9];
    const float* b_kj   = (const float*)d_in[10];
    const float* W_ji   = (const float*)d_in[11];
    const float* b_ji   = (const float*)d_in[12];
    const float* W_down = (const float*)d_in[13];
    const float* W_up   = (const float*)d_in[14];
    const float* rb_W1  = (const float*)d_in[15];
    const float* rb_b1  = (const float*)d_in[16];
    const float* rb_W2  = (const float*)d_in[17];
    const float* rb_b2  = (const float*)d_in[18];
    const float* W_lin  = (const float*)d_in[19];
    const float* b_lin  = (const float*)d_in[20];
    const float* ra_W1  = (const float*)d_in[21];
    const float* ra_b1  = (const float*)d_in[22];
    const float* ra_W2  = (const float*)d_in[23];
    const float* ra_b2  = (const float*)d_in[24];
    float* out = (float*)d_out;

    char* ws = (char*)d_ws;
    size_t off = 0;
    auto alloc = [&](size_t bytes)->char* {
        char* p = ws + off; off += (bytes + 255) & ~(size_t)255; return p;
    };
    float*   W12  = (float*)  alloc(6*256*sizeof(float));
    float*   Wsbf = (float*)  alloc(42*64*sizeof(float));
    ushortT* Wt   = (ushortT*)alloc(11*65536*sizeof(ushortT));
    ushortT* xb   = (ushortT*)alloc((size_t)E_N*H_N*2);
    ushortT* rbe  = (ushortT*)alloc((size_t)E_N*H_N*2);
    ushortT* actA = (ushortT*)alloc((size_t)E_N*H_N*2);
    ushortT* actB = (ushortT*)alloc((size_t)E_N*H_N*2);
    ushortT* actC = (ushortT*)alloc((size_t)E_N*H_N*2);
    float*   down = (float*)  alloc((size_t)E_N*INT_N*4);
    float*   agg  = (float*)  alloc((size_t)E_N*INT_N*4);
    ushortT* aggb = (ushortT*)alloc((size_t)E_N*INT_N*2);

    ushortT* Wt_kj   = Wt + 0*65536;
    ushortT* Wt_ji   = Wt + 1*65536;
    ushortT* Wt_down = Wt + 2*65536;
    ushortT* Wt_up   = Wt + 3*65536;
    ushortT* Wt_rb1  = Wt + 4*65536;
    ushortT* Wt_rb2  = Wt + 5*65536;
    ushortT* Wt_lin  = Wt + 6*65536;
    ushortT* Wt_ra10 = Wt + 7*65536;
    ushortT* Wt_ra11 = Wt + 8*65536;
    ushortT* Wt_ra20 = Wt + 9*65536;
    ushortT* Wt_ra21 = Wt + 10*65536;

    const dim3 blk(256);
    const dim3 g256((E_N+127)/128, 2);
    const dim3 g64 ((E_N+127)/128, 1);

    precompute_w<<<11, blk, 0, stream>>>(W_rbf1, W_rbf2, W_sbf1, W_sbf2, W12, Wsbf);

    WTList L;
    L.src[0]=W_kj;  L.K[0]=256; L.N[0]=256;
    L.src[1]=W_ji;  L.K[1]=256; L.N[1]=256;
    L.src[2]=W_down;L.K[2]=256; L.N[2]=64;
    L.src[3]=W_up;  L.K[3]=64;  L.N[3]=256;
    L.src[4]=rb_W1; L.K[4]=256; L.N[4]=256;
    L.src[5]=rb_W2; L.K[5]=256; L.N[5]=256;
    L.src[6]=W_lin; L.K[6]=256; L.N[6]=256;
    L.src[7]=ra_W1;       L.K[7]=256; L.N[7]=256;
    L.src[8]=ra_W1+65536; L.K[8]=256; L.N[8]=256;
    L.src[9]=ra_W2;       L.K[9]=256; L.N[9]=256;
    L.src[10]=ra_W2+65536;L.K[10]=256;L.N[10]=256;
    transpose_weights<<<dim3(64,11), blk, 0, stream>>>(L, Wt);

    f32_to_bf16_k<<<((size_t)E_N*H_N/8 + 255)/256, blk, 0, stream>>>(x, xb, (long)E_N*H_N);
    rbf_expand<<<E_N, blk, 0, stream>>>(rbf, W12, rbe);

    // x_ji = silu(x@W_ji + b_ji) -> actB
    gemm_mfma<128,4><<<g256, blk, 0, stream>>>(xb, Wt_ji, b_ji, nullptr, nullptr, actB, E_N, 256, 256, 1, 0);
    // x_kj = silu(x@W_kj + b_kj) * rbf_e -> actC
    gemm_mfma<128,4><<<g256, blk, 0, stream>>>(xb, Wt_kj, b_kj, rbe, nullptr, actC, E_N, 256, 256, 1, 0);
    // down = silu(x_kj @ W_down) -> f32 [E,64]
    gemm_mfma<64,2><<<g64, blk, 0, stream>>>(actC, Wt_down, nullptr, nullptr, nullptr, down, E_N, 64, 256, 1, 1);

    zero_f32<<<((long)E_N*INT_N/4 + 255)/256, blk, 0, stream>>>(agg, (long)E_N*INT_N);
    triplet_kernel<<<16384, blk, 0, stream>>>(down, sbf, idx_kj, idx_ji, Wsbf, agg);
    f32_to_bf16_k<<<((size_t)E_N*INT_N/8 + 255)/256, blk, 0, stream>>>(agg, aggb, (long)E_N*INT_N);

    // h = silu(agg@W_up) + x_ji -> actA
    gemm_mfma<128,4><<<g256, blk, 0, stream>>>(aggb, Wt_up, nullptr, nullptr, actB, actA, E_N, 256, 64, 1, 0);
    // before-skip
    gemm_mfma<128,4><<<g256, blk, 0, stream>>>(actA, Wt_rb1, rb_b1, nullptr, nullptr, actC, E_N, 256, 256, 1, 0);
    gemm_mfma<128,4><<<g256, blk, 0, stream>>>(actC, Wt_rb2, rb_b2, nullptr, actA, actB, E_N, 256, 256, 1, 0);
    // h = silu(h@W_lin + b_lin) + x -> actA
    gemm_mfma<128,4><<<g256, blk, 0, stream>>>(actB, Wt_lin, b_lin, nullptr, xb, actA, E_N, 256, 256, 1, 0);
    // after-skip 0
    gemm_mfma<128,4><<<g256, blk, 0, stream>>>(actA, Wt_ra10, ra_b1, nullptr, nullptr, actC, E_N, 256, 256, 1, 0);
    gemm_mfma<128,4><<<g256, blk, 0, stream>>>(actC, Wt_ra20, ra_b2, nullptr, actA, actB, E_N, 256, 256, 1, 0);
    // after-skip 1 (final f32 store to d_out)
    gemm_mfma<128,4><<<g256, blk, 0, stream>>>(actB, Wt_ra11, ra_b1+256, nullptr, nullptr, actC, E_N, 256, 256, 1, 0);
    gemm_mfma<128,4><<<g256, blk, 0, stream>>>(actC, Wt_ra21, ra_b2+256, nullptr, actB, out, E_N, 256, 256, 1, 1);
}